// Round 2
// baseline (26128.741 us; speedup 1.0000x reference)
//
#include <hip/hip_runtime.h>
#include <hip/hip_bf16.h>
#include <math.h>

typedef __bf16 bf16_t;
typedef __bf16 bf16x8 __attribute__((ext_vector_type(8)));
typedef float f32x4 __attribute__((ext_vector_type(4)));

#define B_SZ 1024
#define T_SZ 256
#define PT   5
#define EH   256
#define DH   512
#define ZD   128
#define NMIX 20
#define OUTC 123

__device__ __forceinline__ float fsig(float x) {
    return 1.0f / (1.0f + __expf(-x));
}
__device__ __forceinline__ float ftanh(float x) {
    x = fminf(fmaxf(x, -15.0f), 15.0f);
    float e = __expf(2.0f * x);
    return 1.0f - 2.0f / (e + 1.0f);
}

// ---------------- prep: fp32 -> bf16 weight conversion + zero-padded input-weight tiles
// ranges: [0,65536) wih_s_pad     <- dec_Wih[2048][133] cols 0..4, pad to 32
//         [65536,98304) enc_wih_pad <- enc_Wih_f[1024][5], pad to 32
//         [98304,360448) enc_whh_bf <- enc_Whh_f (262144)
//         [360448,1409024) dec_whh_bf <- dec_Whh (1048576)
//         [1409024,1472000) wout_bf <- W_out (62976)
__global__ void kconv(const float* __restrict__ dec_Wih,
                      const float* __restrict__ enc_Wih_f,
                      const float* __restrict__ enc_Whh_f,
                      const float* __restrict__ dec_Whh,
                      const float* __restrict__ W_out,
                      bf16_t* __restrict__ wih_s_pad,
                      bf16_t* __restrict__ enc_wih_pad,
                      bf16_t* __restrict__ enc_whh_bf,
                      bf16_t* __restrict__ dec_whh_bf,
                      bf16_t* __restrict__ wout_bf) {
    int idx = blockIdx.x * 256 + threadIdx.x;
    if (idx < 65536) {
        int r = idx >> 5, k = idx & 31;
        wih_s_pad[idx] = (k < PT) ? (bf16_t)dec_Wih[r * 133 + k] : (bf16_t)0.0f;
    } else if (idx < 98304) {
        int j = idx - 65536;
        int r = j >> 5, k = j & 31;
        enc_wih_pad[j] = (k < PT) ? (bf16_t)enc_Wih_f[r * PT + k] : (bf16_t)0.0f;
    } else if (idx < 360448) {
        int j = idx - 98304;
        enc_whh_bf[j] = (bf16_t)enc_Whh_f[j];
    } else if (idx < 1409024) {
        int j = idx - 360448;
        dec_whh_bf[j] = (bf16_t)dec_Whh[j];
    } else if (idx < 1472000) {
        int j = idx - 1409024;
        wout_bf[j] = (bf16_t)W_out[j];
    }
}

// ---------------- encoder forward LSTM: 64 blocks x 16 batch rows, 256 steps
__global__ __launch_bounds__(512) void kenc(
        const float* __restrict__ s, const bf16_t* __restrict__ whh,
        const float* __restrict__ bvec, const bf16_t* __restrict__ wih_pad,
        bf16_t* __restrict__ hf_out) {
    __shared__ bf16_t h_sh[16][EH + 8];   // pad 8: keeps 16B-aligned rows, bank spread
    __shared__ bf16_t s_sh[16][40];       // [16][32] zero-padded s tile (+8 pad)
    int tid = threadIdx.x;
    int wid = tid >> 6, lane = tid & 63;
    int q = lane >> 4, n = lane & 15;
    int b0 = blockIdx.x * 16;

    for (int i = tid; i < 16 * (EH + 8); i += 512) h_sh[i / (EH + 8)][i % (EH + 8)] = (bf16_t)0.0f;
    for (int i = tid; i < 16 * 40; i += 512) ((bf16_t*)s_sh)[i] = (bf16_t)0.0f;

    float c_reg[2][4];
    float bias[2][4];
#pragma unroll
    for (int i = 0; i < 2; ++i) {
        int u0 = (wid * 2 + i) * 16;
#pragma unroll
        for (int g = 0; g < 4; ++g) {
            bias[i][g] = bvec[g * EH + u0 + n];
#pragma unroll
            for (int r0 = 0; r0 < 4; ++r0) c_reg[i][r0] = 0.0f;
        }
    }
    __syncthreads();

    for (int t = 0; t < T_SZ; ++t) {
        if (tid < 80) {
            int r = tid / 5, p = tid - r * 5;
            s_sh[r][p] = (bf16_t)s[(size_t)(b0 + r) * (T_SZ * PT) + t * PT + p];
        }
        __syncthreads();   // S1: s staged, prev h writes visible

        f32x4 acc[2][4];
#pragma unroll
        for (int i = 0; i < 2; ++i)
#pragma unroll
            for (int g = 0; g < 4; ++g) acc[i][g] = (f32x4){0.f, 0.f, 0.f, 0.f};

        {   // s tile (K-cols 5..31 are zero on both operands)
            bf16x8 a = *(const bf16x8*)&s_sh[n][q * 8];
#pragma unroll
            for (int i = 0; i < 2; ++i) {
                int u0 = (wid * 2 + i) * 16;
#pragma unroll
                for (int g = 0; g < 4; ++g) {
                    bf16x8 bb = *(const bf16x8*)&wih_pad[(g * EH + u0 + n) * 32 + q * 8];
                    acc[i][g] = __builtin_amdgcn_mfma_f32_16x16x32_bf16(a, bb, acc[i][g], 0, 0, 0);
                }
            }
        }
        for (int kt = 0; kt < EH / 32; ++kt) {
            bf16x8 a = *(const bf16x8*)&h_sh[n][kt * 32 + q * 8];
#pragma unroll
            for (int i = 0; i < 2; ++i) {
                int u0 = (wid * 2 + i) * 16;
#pragma unroll
                for (int g = 0; g < 4; ++g) {
                    bf16x8 bb = *(const bf16x8*)&whh[(size_t)(g * EH + u0 + n) * EH + kt * 32 + q * 8];
                    acc[i][g] = __builtin_amdgcn_mfma_f32_16x16x32_bf16(a, bb, acc[i][g], 0, 0, 0);
                }
            }
        }
        float hreg[2][4];
#pragma unroll
        for (int i = 0; i < 2; ++i)
#pragma unroll
            for (int r = 0; r < 4; ++r) {
                float ig = fsig(acc[i][0][r] + bias[i][0]);
                float fg = fsig(acc[i][1][r] + bias[i][1]);
                float gg = ftanh(acc[i][2][r] + bias[i][2]);
                float og = fsig(acc[i][3][r] + bias[i][3]);
                float c = fg * c_reg[i][r] + ig * gg;
                c_reg[i][r] = c;
                hreg[i][r] = og * ftanh(c);
            }
        __syncthreads();   // S2: all A-frag reads of old h done
#pragma unroll
        for (int i = 0; i < 2; ++i)
#pragma unroll
            for (int r = 0; r < 4; ++r)
                h_sh[q * 4 + r][(wid * 2 + i) * 16 + n] = (bf16_t)hreg[i][r];
        // next-iter S1 protects h reads
    }
    __syncthreads();
    for (int i = tid; i < 16 * EH; i += 512) {
        int r = i >> 8, u = i & 255;
        hf_out[(size_t)(b0 + r) * EH + u] = h_sh[r][u];
    }
}

// ---------------- encoder backward: exactly ONE step from zero state on s[:,T-1,:]
__global__ void kencb(const float* __restrict__ s, const float* __restrict__ wih_b,
                      const float* __restrict__ b_b, bf16_t* __restrict__ hb_out) {
    __shared__ float s_l[5];
    int b = blockIdx.x, u = threadIdx.x;
    if (u < 5) s_l[u] = s[(size_t)b * (T_SZ * PT) + (T_SZ - 1) * PT + u];
    __syncthreads();
    float g4[4];
#pragma unroll
    for (int g = 0; g < 4; ++g) {
        int row = g * EH + u;
        float acc = b_b[row];
#pragma unroll
        for (int p = 0; p < 5; ++p) acc += wih_b[row * 5 + p] * s_l[p];
        g4[g] = acc;
    }
    float c = fsig(g4[0]) * ftanh(g4[2]);   // c_prev = 0
    float h = fsig(g4[3]) * ftanh(c);
    hb_out[(size_t)b * EH + u] = (bf16_t)h;
}

// ---------------- VAE: mu/presig -> z (fp32)
__global__ __launch_bounds__(256) void kv1(
        const bf16_t* __restrict__ hf, const bf16_t* __restrict__ hb,
        const float* __restrict__ W_mu, const float* __restrict__ b_mu,
        const float* __restrict__ W_sig, const float* __restrict__ b_sig,
        const float* __restrict__ eps, float* __restrict__ z_out) {
    __shared__ float hl[16][512];
    __shared__ float ms[16][256];
    int tid = threadIdx.x, b0 = blockIdx.x * 16;
    for (int i = tid; i < 16 * 512; i += 256) {
        int r = i >> 9, k = i & 511;
        hl[r][k] = (k < 256) ? (float)hf[(size_t)(b0 + r) * EH + k]
                             : (float)hb[(size_t)(b0 + r) * EH + (k - 256)];
    }
    __syncthreads();
    int r = tid >> 4, c0 = tid & 15;
    for (int i = 0; i < 16; ++i) {
        int c = c0 + 16 * i;
        const float* wrow = (c < 128) ? &W_mu[c * 512] : &W_sig[(c - 128) * 512];
        float acc = (c < 128) ? b_mu[c] : b_sig[c - 128];
        for (int k = 0; k < 512; k += 4) {
            f32x4 w4 = *(const f32x4*)&wrow[k];
            f32x4 x4 = *(const f32x4*)&hl[r][k];
#pragma unroll
            for (int j = 0; j < 4; ++j) acc += w4[j] * x4[j];
        }
        ms[r][c] = acc;
    }
    __syncthreads();
    for (int i = tid; i < 16 * 128; i += 256) {
        int r2 = i >> 7, zi = i & 127;
        float mu = ms[r2][zi], ps = ms[r2][128 + zi];
        z_out[(size_t)(b0 + r2) * ZD + zi] =
            mu + __expf(0.5f * ps) * eps[(size_t)(b0 + r2) * ZD + zi];
    }
}

// ---------------- h0 = tanh(z@W_h0.T+b) (bf16) and zproj = z@Wih_z.T + dec_b (fp32)
__global__ __launch_bounds__(256) void kv2(
        const float* __restrict__ z, const float* __restrict__ W_h0,
        const float* __restrict__ b_h0, const float* __restrict__ dec_Wih,
        const float* __restrict__ dec_b, bf16_t* __restrict__ h0_out,
        float* __restrict__ zproj_out) {
    __shared__ float zl[16][128];
    int bg = blockIdx.x >> 4, cg = blockIdx.x & 15;
    int b0 = bg * 16, tid = threadIdx.x;
    for (int i = tid; i < 16 * 128; i += 256) {
        int r = i >> 7, k = i & 127;
        zl[r][k] = z[(size_t)(b0 + r) * ZD + k];
    }
    __syncthreads();
    int r = tid & 15, c0 = tid >> 4;
    for (int i = 0; i < 10; ++i) {
        int c = cg * 160 + c0 + 16 * i;
        if (c < 512) {
            const float* wrow = &W_h0[c * 128];
            float acc = b_h0[c];
            for (int k = 0; k < 128; ++k) acc += wrow[k] * zl[r][k];
            h0_out[(size_t)(b0 + r) * DH + c] = (bf16_t)ftanh(acc);
        } else {
            int gc = c - 512;
            const float* wrow = &dec_Wih[gc * 133 + 5];
            float acc = dec_b[gc];
            for (int k = 0; k < 128; ++k) acc += wrow[k] * zl[r][k];
            zproj_out[(size_t)(b0 + r) * 2048 + gc] = acc;
        }
    }
}

// ---------------- decoder: 64 blocks x 16 batch rows, 256 steps, fused epilogue
__global__ __launch_bounds__(512) void kdec(
        const float* __restrict__ s, const bf16_t* __restrict__ whh,
        const bf16_t* __restrict__ wih_s_pad, const float* __restrict__ zproj,
        const bf16_t* __restrict__ h0, const bf16_t* __restrict__ wout,
        const float* __restrict__ b_out, float* __restrict__ out) {
    __shared__ bf16_t h_sh[16][DH + 8];   // 520
    __shared__ bf16_t s_sh[16][40];
    __shared__ float y_sh[16][132];
    __shared__ float pie[16][NMIX];
    __shared__ float pisum[16];
    __shared__ float bout_sh[128];

    int tid = threadIdx.x;
    int wid = tid >> 6, lane = tid & 63;
    int q = lane >> 4, n = lane & 15;
    int b0 = blockIdx.x * 16;

    for (int i = tid; i < 16 * (DH + 8); i += 512) {
        int r = i / (DH + 8), c = i - r * (DH + 8);
        h_sh[r][c] = (c < DH) ? h0[(size_t)(b0 + r) * DH + c] : (bf16_t)0.0f;
    }
    for (int i = tid; i < 16 * 40; i += 512) ((bf16_t*)s_sh)[i] = (bf16_t)0.0f;
    if (tid < 128) bout_sh[tid] = (tid < OUTC) ? b_out[tid] : 0.0f;

    float c_reg[4][4];
#pragma unroll
    for (int i = 0; i < 4; ++i)
#pragma unroll
        for (int r = 0; r < 4; ++r) c_reg[i][r] = 0.0f;

    int ycol = wid * 16 + n;
    const bf16_t* wout_row = &wout[(size_t)(ycol < OUTC ? ycol : 0) * DH];
    __syncthreads();

    for (int t = 0; t < T_SZ; ++t) {
        if (tid < 80) {
            int r = tid / 5, p = tid - r * 5;
            s_sh[r][p] = (t == 0) ? (bf16_t)(p == 2 ? 1.0f : 0.0f)
                                  : (bf16_t)s[(size_t)(b0 + r) * (T_SZ * PT) + (t - 1) * PT + p];
        }
        __syncthreads();   // S1

        f32x4 acc[4][4];
#pragma unroll
        for (int i = 0; i < 4; ++i)
#pragma unroll
            for (int g = 0; g < 4; ++g) acc[i][g] = (f32x4){0.f, 0.f, 0.f, 0.f};

        {   // s tile
            bf16x8 a = *(const bf16x8*)&s_sh[n][q * 8];
#pragma unroll
            for (int i = 0; i < 4; ++i) {
                int u0 = (wid * 4 + i) * 16;
#pragma unroll
                for (int g = 0; g < 4; ++g) {
                    bf16x8 bb = *(const bf16x8*)&wih_s_pad[(g * DH + u0 + n) * 32 + q * 8];
                    acc[i][g] = __builtin_amdgcn_mfma_f32_16x16x32_bf16(a, bb, acc[i][g], 0, 0, 0);
                }
            }
        }
        for (int kt = 0; kt < DH / 32; ++kt) {
            bf16x8 a = *(const bf16x8*)&h_sh[n][kt * 32 + q * 8];
#pragma unroll
            for (int i = 0; i < 4; ++i) {
                int u0 = (wid * 4 + i) * 16;
#pragma unroll
                for (int g = 0; g < 4; ++g) {
                    bf16x8 bb = *(const bf16x8*)&whh[(size_t)(g * DH + u0 + n) * DH + kt * 32 + q * 8];
                    acc[i][g] = __builtin_amdgcn_mfma_f32_16x16x32_bf16(a, bb, acc[i][g], 0, 0, 0);
                }
            }
        }
        float hreg[4][4];
#pragma unroll
        for (int i = 0; i < 4; ++i) {
            int u0 = (wid * 4 + i) * 16;
#pragma unroll
            for (int r = 0; r < 4; ++r) {
                int m = q * 4 + r;
                size_t zb = (size_t)(b0 + m) * 2048 + u0 + n;
                float ig = fsig(acc[i][0][r] + zproj[zb]);
                float fg = fsig(acc[i][1][r] + zproj[zb + DH]);
                float gg = ftanh(acc[i][2][r] + zproj[zb + 2 * DH]);
                float og = fsig(acc[i][3][r] + zproj[zb + 3 * DH]);
                float c = fg * c_reg[i][r] + ig * gg;
                c_reg[i][r] = c;
                hreg[i][r] = og * ftanh(c);
            }
        }
        __syncthreads();   // S2
#pragma unroll
        for (int i = 0; i < 4; ++i)
#pragma unroll
            for (int r = 0; r < 4; ++r)
                h_sh[q * 4 + r][(wid * 4 + i) * 16 + n] = (bf16_t)hreg[i][r];
        __syncthreads();   // S3
        {   // y = h@W_out.T + b_out ; wave wid owns output cols wid*16+n
            f32x4 yacc = (f32x4){0.f, 0.f, 0.f, 0.f};
#pragma unroll
            for (int kt = 0; kt < DH / 32; ++kt) {
                bf16x8 a = *(const bf16x8*)&h_sh[n][kt * 32 + q * 8];
                bf16x8 bb = *(const bf16x8*)&wout_row[kt * 32 + q * 8];
                yacc = __builtin_amdgcn_mfma_f32_16x16x32_bf16(a, bb, yacc, 0, 0, 0);
            }
            if (ycol < OUTC) {
#pragma unroll
                for (int r = 0; r < 4; ++r)
                    y_sh[q * 4 + r][ycol] = yacc[r] + bout_sh[ycol];
            }
        }
        __syncthreads();   // S4
        if (tid < 16) {
            float ssum = 0.0f;
#pragma unroll
            for (int j = 0; j < NMIX; ++j) {
                float e = __expf(y_sh[tid][6 * j]);
                pie[tid][j] = e;
                ssum += e;
            }
            pisum[tid] = 1.0f / ssum;
        }
        __syncthreads();   // S5
        size_t obase = ((size_t)t * B_SZ + b0) * OUTC;
        for (int idx = tid; idx < 16 * OUTC; idx += 512) {
            int r = idx / OUTC, c = idx - r * OUTC;
            float val;
            if (c < 20)       val = pie[r][c] * pisum[r];
            else if (c < 40)  val = y_sh[r][(c - 20) * 6 + 1];
            else if (c < 60)  val = y_sh[r][(c - 40) * 6 + 2];
            else if (c < 80)  val = __expf(y_sh[r][(c - 60) * 6 + 3]);
            else if (c < 100) val = __expf(y_sh[r][(c - 80) * 6 + 4]);
            else if (c < 120) val = ftanh(y_sh[r][(c - 100) * 6 + 5]);
            else              val = __expf(y_sh[r][c]);   // raw exp; kqk normalizes
            out[obase + idx] = val;
        }
        // next-iter S1 protects y_sh/pie reuse
    }
}

// ---------------- global qk normalization per timestep
__global__ __launch_bounds__(256) void kqk(float* __restrict__ out) {
    __shared__ float red[256];
    int t = blockIdx.x, tid = threadIdx.x;
    float lsum = 0.0f;
    for (int b = tid; b < B_SZ; b += 256) {
        size_t base = ((size_t)t * B_SZ + b) * OUTC + 120;
        lsum += out[base] + out[base + 1] + out[base + 2];
    }
    red[tid] = lsum;
    __syncthreads();
    for (int s2 = 128; s2 > 0; s2 >>= 1) {
        if (tid < s2) red[tid] += red[tid + s2];
        __syncthreads();
    }
    float inv = 1.0f / red[0];
    for (int b = tid; b < B_SZ; b += 256) {
        size_t base = ((size_t)t * B_SZ + b) * OUTC + 120;
        out[base]     *= inv;
        out[base + 1] *= inv;
        out[base + 2] *= inv;
    }
}

extern "C" void kernel_launch(void* const* d_in, const int* in_sizes, int n_in,
                              void* d_out, int out_size, void* d_ws, size_t ws_size,
                              hipStream_t stream) {
    const float* s         = (const float*)d_in[0];
    const float* eps       = (const float*)d_in[1];
    const float* enc_Wih_f = (const float*)d_in[2];
    const float* enc_Whh_f = (const float*)d_in[3];
    const float* enc_b_f   = (const float*)d_in[4];
    const float* enc_Wih_b = (const float*)d_in[5];
    // d_in[6] enc_Whh_b unused: backward dir contributes only its step on s[:,T-1]
    const float* enc_b_b   = (const float*)d_in[7];
    const float* W_mu      = (const float*)d_in[8];
    const float* b_mu      = (const float*)d_in[9];
    const float* W_sig     = (const float*)d_in[10];
    const float* b_sig     = (const float*)d_in[11];
    const float* W_h0      = (const float*)d_in[12];
    const float* b_h0      = (const float*)d_in[13];
    const float* dec_Wih   = (const float*)d_in[14];
    const float* dec_Whh   = (const float*)d_in[15];
    const float* dec_b     = (const float*)d_in[16];
    const float* W_out     = (const float*)d_in[17];
    const float* b_out     = (const float*)d_in[18];

    char* ws = (char*)d_ws;
    bf16_t* wih_s_pad   = (bf16_t*)(ws + 0);         // 65536 bf16   = 128KB
    bf16_t* enc_wih_pad = (bf16_t*)(ws + 131072);    // 32768 bf16   = 64KB
    bf16_t* enc_whh_bf  = (bf16_t*)(ws + 196608);    // 262144 bf16  = 512KB
    bf16_t* dec_whh_bf  = (bf16_t*)(ws + 720896);    // 1048576 bf16 = 2MB
    bf16_t* wout_bf     = (bf16_t*)(ws + 2818048);   // 62976 bf16   = 123KB
    bf16_t* hf          = (bf16_t*)(ws + 2944000);   // 1024*256 bf16
    bf16_t* hb          = (bf16_t*)(ws + 3468288);   // 1024*256 bf16
    bf16_t* h0          = (bf16_t*)(ws + 3992576);   // 1024*512 bf16
    float*  z           = (float*) (ws + 5041152);   // 1024*128 f32
    float*  zproj       = (float*) (ws + 5565440);   // 1024*2048 f32 (8MB)
    // total ws use: ~13.3 MB

    kconv<<<5750, 256, 0, stream>>>(dec_Wih, enc_Wih_f, enc_Whh_f, dec_Whh, W_out,
                                    wih_s_pad, enc_wih_pad, enc_whh_bf, dec_whh_bf, wout_bf);
    kenc<<<64, 512, 0, stream>>>(s, enc_whh_bf, enc_b_f, enc_wih_pad, hf);
    kencb<<<1024, 256, 0, stream>>>(s, enc_Wih_b, enc_b_b, hb);
    kv1<<<64, 256, 0, stream>>>(hf, hb, W_mu, b_mu, W_sig, b_sig, eps, z);
    kv2<<<1024, 256, 0, stream>>>(z, W_h0, b_h0, dec_Wih, dec_b, h0, zproj);
    kdec<<<64, 512, 0, stream>>>(s, dec_whh_bf, wih_s_pad, zproj, h0, wout_bf, b_out,
                                 (float*)d_out);
    kqk<<<256, 256, 0, stream>>>((float*)d_out);
}

// Round 4
// 8722.621 us; speedup vs baseline: 2.9955x; 2.9955x over previous
//
#include <hip/hip_runtime.h>
#include <hip/hip_bf16.h>
#include <math.h>

typedef __bf16 bf16_t;
typedef __bf16 bf16x8 __attribute__((ext_vector_type(8)));
typedef float f32x4 __attribute__((ext_vector_type(4)));

#define B_SZ 1024
#define T_SZ 256
#define PT   5
#define EH   256
#define DH   512
#define ZD   128
#define NMIX 20
#define OUTC 123

__device__ __forceinline__ float fsig(float x) {
    return 1.0f / (1.0f + __expf(-x));
}
__device__ __forceinline__ float ftanh(float x) {
    x = fminf(fmaxf(x, -15.0f), 15.0f);
    float e = __expf(2.0f * x);
    return 1.0f - 2.0f / (e + 1.0f);
}

// ---------------- prep: fp32->bf16 weights, padded tiles, zero flags
__global__ void kconv(const float* __restrict__ dec_Wih,
                      const float* __restrict__ enc_Wih_f,
                      const float* __restrict__ enc_Whh_f,
                      const float* __restrict__ dec_Whh,
                      const float* __restrict__ W_out,
                      bf16_t* __restrict__ wih_s_pad,
                      bf16_t* __restrict__ enc_wih_pad,
                      bf16_t* __restrict__ enc_whh_bf,
                      bf16_t* __restrict__ dec_whh_bf,
                      bf16_t* __restrict__ wout_pad,
                      int* __restrict__ flags_e,
                      int* __restrict__ flags_d) {
    int idx = blockIdx.x * 256 + threadIdx.x;
    if (blockIdx.x == 0 && threadIdx.x < 256) {
        flags_e[threadIdx.x] = 0;
        flags_d[threadIdx.x] = 0;
    }
    if (idx < 65536) {
        int r = idx >> 5, k = idx & 31;
        wih_s_pad[idx] = (k < PT) ? (bf16_t)dec_Wih[r * 133 + k] : (bf16_t)0.0f;
    } else if (idx < 98304) {
        int j = idx - 65536;
        int r = j >> 5, k = j & 31;
        enc_wih_pad[j] = (k < PT) ? (bf16_t)enc_Wih_f[r * PT + k] : (bf16_t)0.0f;
    } else if (idx < 360448) {
        int j = idx - 98304;
        enc_whh_bf[j] = (bf16_t)enc_Whh_f[j];
    } else if (idx < 1409024) {
        int j = idx - 360448;
        dec_whh_bf[j] = (bf16_t)dec_Whh[j];
    } else if (idx < 1474560) {
        int j = idx - 1409024;
        int r = j >> 9, k = j & 511;
        wout_pad[j] = (r < OUTC) ? (bf16_t)W_out[r * DH + k] : (bf16_t)0.0f;
    }
}

// ---------------- persistent encoder fwd LSTM: 256 blocks = 16 groups x 16 slices
// weights in registers, h in LDS, per-step sibling exchange via ping-pong hg + flags
// NOTE: regular launch (grid == 256 == #CUs, 1 block/CU -> all blocks co-resident);
// cooperative launch is NOT supported by this harness (silent failure in r3).
__global__ __launch_bounds__(256, 1) void kenc_p(
        const float* __restrict__ s, const bf16_t* __restrict__ whh,
        const float* __restrict__ bvec, const bf16_t* __restrict__ wih_pad,
        bf16_t* __restrict__ hg, int* __restrict__ flags) {
    __shared__ bf16_t h_sh[64][296];      // 288+8 pad; 296*2=592B=37*16 (odd*16)
    __shared__ float gates_sh[64][64];
    int tid = threadIdx.x, bid = blockIdx.x;
    int g = bid & 15, j = bid >> 4;       // siblings (same g) share XCD slot: bid%8=g%8
    int w = tid >> 6, lane = tid & 63, q = lane >> 4, n = lane & 15;

    for (int i = tid; i < 64 * 296; i += 256) ((bf16_t*)h_sh)[i] = (bf16_t)0.0f;

    // wave w = gate w; N-col nu = w*16+n -> weight row r_g
    int r_g = w * 256 + j * 16 + n;
    bf16x8 bw[9];
#pragma unroll
    for (int kt = 0; kt < 8; ++kt)
        bw[kt] = *(const bf16x8*)&whh[(size_t)r_g * 256 + kt * 32 + q * 8];
    bw[8] = *(const bf16x8*)&wih_pad[r_g * 32 + q * 8];

    int uu = tid & 15, rg = tid >> 4;     // pointwise: unit uu, rows rg+16k
    float bias_g[4];
#pragma unroll
    for (int gp = 0; gp < 4; ++gp) bias_g[gp] = bvec[gp * 256 + j * 16 + uu];
    float c_reg[4] = {0.f, 0.f, 0.f, 0.f};
    __syncthreads();

    for (int t = 0; t < T_SZ; ++t) {
        if (t > 0) {
            if (tid < 16) {
                int it = 0;
                while (__hip_atomic_load(&flags[g * 16 + tid], __ATOMIC_ACQUIRE,
                                         __HIP_MEMORY_SCOPE_AGENT) < t) {
                    __builtin_amdgcn_s_sleep(2);
                    if (++it > (1 << 17)) break;
                }
            }
            __syncthreads();
            const bf16_t* src = hg + ((size_t)((t + 1) & 1)) * (1024 * 256);
            for (int i = tid; i < 2048; i += 256) {
                int row = i >> 5, c8 = (i & 31) * 8;
                *(bf16x8*)&h_sh[row][c8] =
                    *(const bf16x8*)&src[(size_t)(g * 64 + row) * 256 + c8];
            }
        }
        if (tid < 64) {
            const float* sp = &s[(size_t)(g * 64 + tid) * (T_SZ * PT) + (size_t)t * PT];
#pragma unroll
            for (int p = 0; p < 5; ++p) h_sh[tid][256 + p] = (bf16_t)sp[p];
        }
        __syncthreads();

        f32x4 acc[4];
#pragma unroll
        for (int m = 0; m < 4; ++m) acc[m] = (f32x4){0.f, 0.f, 0.f, 0.f};
#pragma unroll
        for (int kt = 0; kt < 9; ++kt)
#pragma unroll
            for (int m = 0; m < 4; ++m) {
                bf16x8 a = *(const bf16x8*)&h_sh[m * 16 + n][kt * 32 + q * 8];
                acc[m] = __builtin_amdgcn_mfma_f32_16x16x32_bf16(a, bw[kt], acc[m], 0, 0, 0);
            }
#pragma unroll
        for (int m = 0; m < 4; ++m)
#pragma unroll
            for (int r = 0; r < 4; ++r)
                gates_sh[m * 16 + q * 4 + r][w * 16 + n] = acc[m][r];
        __syncthreads();

        bf16_t* dst = hg + ((size_t)(t & 1)) * (1024 * 256);
#pragma unroll
        for (int k = 0; k < 4; ++k) {
            int row = rg + 16 * k;
            float ig = fsig(gates_sh[row][0 * 16 + uu] + bias_g[0]);
            float fg = fsig(gates_sh[row][1 * 16 + uu] + bias_g[1]);
            float gg = ftanh(gates_sh[row][2 * 16 + uu] + bias_g[2]);
            float og = fsig(gates_sh[row][3 * 16 + uu] + bias_g[3]);
            float c = fg * c_reg[k] + ig * gg;
            c_reg[k] = c;
            dst[(size_t)(g * 64 + row) * 256 + j * 16 + uu] = (bf16_t)(og * ftanh(c));
        }
        __syncthreads();
        if (tid == 0) {
            __threadfence();
            __hip_atomic_store(&flags[g * 16 + j], t + 1, __ATOMIC_RELEASE,
                               __HIP_MEMORY_SCOPE_AGENT);
        }
    }
}

// ---------------- encoder backward: ONE step from zero state on s[:,T-1,:]
__global__ void kencb(const float* __restrict__ s, const float* __restrict__ wih_b,
                      const float* __restrict__ b_b, bf16_t* __restrict__ hb_out) {
    __shared__ float s_l[5];
    int b = blockIdx.x, u = threadIdx.x;
    if (u < 5) s_l[u] = s[(size_t)b * (T_SZ * PT) + (T_SZ - 1) * PT + u];
    __syncthreads();
    float g4[4];
#pragma unroll
    for (int g = 0; g < 4; ++g) {
        int row = g * EH + u;
        float acc = b_b[row];
#pragma unroll
        for (int p = 0; p < 5; ++p) acc += wih_b[row * 5 + p] * s_l[p];
        g4[g] = acc;
    }
    float c = fsig(g4[0]) * ftanh(g4[2]);
    float h = fsig(g4[3]) * ftanh(c);
    hb_out[(size_t)b * EH + u] = (bf16_t)h;
}

// ---------------- VAE: mu/presig -> z (fp32)
__global__ __launch_bounds__(256) void kv1(
        const bf16_t* __restrict__ hf, const bf16_t* __restrict__ hb,
        const float* __restrict__ W_mu, const float* __restrict__ b_mu,
        const float* __restrict__ W_sig, const float* __restrict__ b_sig,
        const float* __restrict__ eps, float* __restrict__ z_out) {
    __shared__ float hl[16][512];
    __shared__ float ms[16][256];
    int tid = threadIdx.x, b0 = blockIdx.x * 16;
    for (int i = tid; i < 16 * 512; i += 256) {
        int r = i >> 9, k = i & 511;
        hl[r][k] = (k < 256) ? (float)hf[(size_t)(b0 + r) * EH + k]
                             : (float)hb[(size_t)(b0 + r) * EH + (k - 256)];
    }
    __syncthreads();
    int r = tid >> 4, c0 = tid & 15;
    for (int i = 0; i < 16; ++i) {
        int c = c0 + 16 * i;
        const float* wrow = (c < 128) ? &W_mu[c * 512] : &W_sig[(c - 128) * 512];
        float acc = (c < 128) ? b_mu[c] : b_sig[c - 128];
        for (int k = 0; k < 512; k += 4) {
            f32x4 w4 = *(const f32x4*)&wrow[k];
            f32x4 x4 = *(const f32x4*)&hl[r][k];
#pragma unroll
            for (int jj = 0; jj < 4; ++jj) acc += w4[jj] * x4[jj];
        }
        ms[r][c] = acc;
    }
    __syncthreads();
    for (int i = tid; i < 16 * 128; i += 256) {
        int r2 = i >> 7, zi = i & 127;
        float mu = ms[r2][zi], ps = ms[r2][128 + zi];
        z_out[(size_t)(b0 + r2) * ZD + zi] =
            mu + __expf(0.5f * ps) * eps[(size_t)(b0 + r2) * ZD + zi];
    }
}

// ---------------- h0 = tanh(z@W_h0.T+b) (bf16, into hg parity-1) and zproj (fp32)
__global__ __launch_bounds__(256) void kv2(
        const float* __restrict__ z, const float* __restrict__ W_h0,
        const float* __restrict__ b_h0, const float* __restrict__ dec_Wih,
        const float* __restrict__ dec_b, bf16_t* __restrict__ h0_out,
        float* __restrict__ zproj_out) {
    __shared__ float zl[16][128];
    int bg = blockIdx.x >> 4, cg = blockIdx.x & 15;
    int b0 = bg * 16, tid = threadIdx.x;
    for (int i = tid; i < 16 * 128; i += 256) {
        int r = i >> 7, k = i & 127;
        zl[r][k] = z[(size_t)(b0 + r) * ZD + k];
    }
    __syncthreads();
    int r = tid & 15, c0 = tid >> 4;
    for (int i = 0; i < 10; ++i) {
        int c = cg * 160 + c0 + 16 * i;
        if (c < 512) {
            const float* wrow = &W_h0[c * 128];
            float acc = b_h0[c];
            for (int k = 0; k < 128; ++k) acc += wrow[k] * zl[r][k];
            h0_out[(size_t)(b0 + r) * DH + c] = (bf16_t)ftanh(acc);
        } else {
            int gc = c - 512;
            const float* wrow = &dec_Wih[gc * 133 + 5];
            float acc = dec_b[gc];
            for (int k = 0; k < 128; ++k) acc += wrow[k] * zl[r][k];
            zproj_out[(size_t)(b0 + r) * 2048 + gc] = acc;
        }
    }
}

// ---------------- persistent decoder: 256 blocks = 16 groups(M=64) x 16 slices(32 units)
__global__ __launch_bounds__(256, 1) void kdec_p(
        const float* __restrict__ s, const bf16_t* __restrict__ whh,
        const bf16_t* __restrict__ wih_s_pad, const float* __restrict__ zproj,
        const bf16_t* __restrict__ wout_pad, const float* __restrict__ b_out,
        bf16_t* __restrict__ hg, int* __restrict__ flags,
        float* __restrict__ out) {
    __shared__ bf16_t h_sh[64][552];      // 544+8; 552*2=1104B=69*16 (odd*16)
    __shared__ float gates_sh[64][128];   // total static LDS ~103KB (<160KB gfx950 max)
    int tid = threadIdx.x, bid = blockIdx.x;
    int g = bid & 15, j = bid >> 4;
    int w = tid >> 6, lane = tid & 63, q = lane >> 4, n = lane & 15;
    int mt_y = j >> 2, nq = j & 3;        // y-GEMM assignment: M-tile, N-quarter

    for (int i = tid; i < 64 * 552; i += 256) ((bf16_t*)h_sh)[i] = (bf16_t)0.0f;

    // main weights: wave owns N-tiles {w, w+4}; nu=ntv*16+n -> gate=nu>>5, unit=nu&31
    bf16x8 bw[2][17];
#pragma unroll
    for (int idx = 0; idx < 2; ++idx) {
        int ntv = w + idx * 4;
        int r_g = (ntv >> 1) * 512 + j * 32 + (ntv & 1) * 16 + n;
#pragma unroll
        for (int kt = 0; kt < 16; ++kt)
            bw[idx][kt] = *(const bf16x8*)&whh[(size_t)r_g * 512 + kt * 32 + q * 8];
        bw[idx][16] = *(const bf16x8*)&wih_s_pad[r_g * 32 + q * 8];
    }
    // y weights (used by waves 0,1): out col cy
    int cy = nq * 32 + w * 16 + n;
    int cyc = (w < 2) ? cy : 0;
    bf16x8 bwy[16];
#pragma unroll
    for (int kt = 0; kt < 16; ++kt)
        bwy[kt] = *(const bf16x8*)&wout_pad[(size_t)cyc * 512 + kt * 32 + q * 8];
    float by = (cyc < OUTC) ? b_out[cyc] : 0.0f;
    int py = (cyc < 120) ? (cyc % 6) * 20 + cyc / 6 : cyc;   // raw-y -> final position

    int uu = tid & 31, rg2 = tid >> 5;    // pointwise: unit uu, rows rg2+8k
    float zp[8][4];
#pragma unroll
    for (int k = 0; k < 8; ++k)
#pragma unroll
        for (int gp = 0; gp < 4; ++gp)
            zp[k][gp] = zproj[(size_t)(g * 64 + rg2 + 8 * k) * 2048 + gp * 512 + j * 32 + uu];
    float c_reg[8];
#pragma unroll
    for (int k = 0; k < 8; ++k) c_reg[k] = 0.f;
    __syncthreads();

    for (int t = 0; t < T_SZ; ++t) {
        if (t > 0) {
            if (tid < 16) {
                int it = 0;
                while (__hip_atomic_load(&flags[g * 16 + tid], __ATOMIC_ACQUIRE,
                                         __HIP_MEMORY_SCOPE_AGENT) < t) {
                    __builtin_amdgcn_s_sleep(2);
                    if (++it > (1 << 17)) break;
                }
            }
            __syncthreads();
        }
        // stage h(t-1): parity (t-1)&1 == (t+1)&1 ; t=0 reads h0 (kv2 wrote parity 1)
        const bf16_t* src = hg + ((size_t)((t + 1) & 1)) * (1024 * 512);
        for (int i = tid; i < 4096; i += 256) {
            int row = i >> 6, c8 = (i & 63) * 8;
            *(bf16x8*)&h_sh[row][c8] =
                *(const bf16x8*)&src[(size_t)(g * 64 + row) * 512 + c8];
        }
        if (tid < 64) {
            if (t == 0) {
#pragma unroll
                for (int p = 0; p < 5; ++p)
                    h_sh[tid][512 + p] = (bf16_t)((p == 2) ? 1.0f : 0.0f);
            } else {
                const float* sp = &s[(size_t)(g * 64 + tid) * (T_SZ * PT) + (size_t)(t - 1) * PT];
#pragma unroll
                for (int p = 0; p < 5; ++p) h_sh[tid][512 + p] = (bf16_t)sp[p];
            }
        }
        __syncthreads();

        // y(t-1) = h(t-1) @ W_out.T (+bias): waves 0,1; raw values to d_out
        if (t > 0 && w < 2) {
            f32x4 ya = (f32x4){0.f, 0.f, 0.f, 0.f};
#pragma unroll
            for (int kt = 0; kt < 16; ++kt) {
                bf16x8 a = *(const bf16x8*)&h_sh[mt_y * 16 + n][kt * 32 + q * 8];
                ya = __builtin_amdgcn_mfma_f32_16x16x32_bf16(a, bwy[kt], ya, 0, 0, 0);
            }
            if (cy < OUTC) {
#pragma unroll
                for (int r = 0; r < 4; ++r)
                    out[((size_t)(t - 1) * B_SZ + g * 64 + mt_y * 16 + q * 4 + r) * OUTC + py] =
                        ya[r] + by;
            }
        }

        // main gates GEMM
        f32x4 acc[4][2];
#pragma unroll
        for (int m = 0; m < 4; ++m) {
            acc[m][0] = (f32x4){0.f, 0.f, 0.f, 0.f};
            acc[m][1] = (f32x4){0.f, 0.f, 0.f, 0.f};
        }
#pragma unroll
        for (int kt = 0; kt < 17; ++kt)
#pragma unroll
            for (int m = 0; m < 4; ++m) {
                bf16x8 a = *(const bf16x8*)&h_sh[m * 16 + n][kt * 32 + q * 8];
                acc[m][0] = __builtin_amdgcn_mfma_f32_16x16x32_bf16(a, bw[0][kt], acc[m][0], 0, 0, 0);
                acc[m][1] = __builtin_amdgcn_mfma_f32_16x16x32_bf16(a, bw[1][kt], acc[m][1], 0, 0, 0);
            }
#pragma unroll
        for (int idx = 0; idx < 2; ++idx) {
            int colb = (w + idx * 4) * 16 + n;
#pragma unroll
            for (int m = 0; m < 4; ++m)
#pragma unroll
                for (int r = 0; r < 4; ++r)
                    gates_sh[m * 16 + q * 4 + r][colb] = acc[m][idx][r];
        }
        __syncthreads();

        bf16_t* dst = hg + ((size_t)(t & 1)) * (1024 * 512);
#pragma unroll
        for (int k = 0; k < 8; ++k) {
            int row = rg2 + 8 * k;
            float ig = fsig(gates_sh[row][0 * 32 + uu] + zp[k][0]);
            float fg = fsig(gates_sh[row][1 * 32 + uu] + zp[k][1]);
            float gg = ftanh(gates_sh[row][2 * 32 + uu] + zp[k][2]);
            float og = fsig(gates_sh[row][3 * 32 + uu] + zp[k][3]);
            float c = fg * c_reg[k] + ig * gg;
            c_reg[k] = c;
            dst[(size_t)(g * 64 + row) * 512 + j * 32 + uu] = (bf16_t)(og * ftanh(c));
        }
        __syncthreads();
        if (tid == 0) {
            __threadfence();
            __hip_atomic_store(&flags[g * 16 + j], t + 1, __ATOMIC_RELEASE,
                               __HIP_MEMORY_SCOPE_AGENT);
        }
    }

    // final y(255)
    if (tid < 16) {
        int it = 0;
        while (__hip_atomic_load(&flags[g * 16 + tid], __ATOMIC_ACQUIRE,
                                 __HIP_MEMORY_SCOPE_AGENT) < T_SZ) {
            __builtin_amdgcn_s_sleep(2);
            if (++it > (1 << 17)) break;
        }
    }
    __syncthreads();
    const bf16_t* src = hg + (size_t)1 * (1024 * 512);   // 255&1 == 1
    for (int i = tid; i < 4096; i += 256) {
        int row = i >> 6, c8 = (i & 63) * 8;
        *(bf16x8*)&h_sh[row][c8] = *(const bf16x8*)&src[(size_t)(g * 64 + row) * 512 + c8];
    }
    __syncthreads();
    if (w < 2) {
        f32x4 ya = (f32x4){0.f, 0.f, 0.f, 0.f};
#pragma unroll
        for (int kt = 0; kt < 16; ++kt) {
            bf16x8 a = *(const bf16x8*)&h_sh[mt_y * 16 + n][kt * 32 + q * 8];
            ya = __builtin_amdgcn_mfma_f32_16x16x32_bf16(a, bwy[kt], ya, 0, 0, 0);
        }
        if (cy < OUTC) {
#pragma unroll
            for (int r = 0; r < 4; ++r)
                out[((size_t)(T_SZ - 1) * B_SZ + g * 64 + mt_y * 16 + q * 4 + r) * OUTC + py] =
                    ya[r] + by;
        }
    }
}

// ---------------- post: mixture transforms on raw y (row-local)
__global__ __launch_bounds__(256) void kpost(float* __restrict__ out) {
    __shared__ float buf[128][OUTC];
    int bid = blockIdx.x, tid = threadIdx.x;
    float* base = out + (size_t)bid * 128 * OUTC;
    for (int i = tid; i < 128 * OUTC / 4; i += 256)
        ((f32x4*)buf)[i] = ((const f32x4*)base)[i];
    __syncthreads();
    int row = tid >> 1, half = tid & 1;
    if (half == 0) {
        float e[20], ssum = 0.f;
#pragma unroll
        for (int m = 0; m < 20; ++m) { e[m] = __expf(buf[row][m]); ssum += e[m]; }
        float inv = 1.0f / ssum;
#pragma unroll
        for (int m = 0; m < 20; ++m) buf[row][m] = e[m] * inv;
#pragma unroll
        for (int m = 60; m < 80; ++m) buf[row][m] = __expf(buf[row][m]);
    } else {
#pragma unroll
        for (int m = 80; m < 100; ++m) buf[row][m] = __expf(buf[row][m]);
#pragma unroll
        for (int m = 100; m < 120; ++m) buf[row][m] = ftanh(buf[row][m]);
#pragma unroll
        for (int m = 120; m < OUTC; ++m) buf[row][m] = __expf(buf[row][m]);
    }
    __syncthreads();
    for (int i = tid; i < 128 * OUTC / 4; i += 256)
        ((f32x4*)base)[i] = ((f32x4*)buf)[i];
}

// ---------------- global qk normalization per timestep
__global__ __launch_bounds__(256) void kqk(float* __restrict__ out) {
    __shared__ float red[256];
    int t = blockIdx.x, tid = threadIdx.x;
    float lsum = 0.0f;
    for (int b = tid; b < B_SZ; b += 256) {
        size_t base = ((size_t)t * B_SZ + b) * OUTC + 120;
        lsum += out[base] + out[base + 1] + out[base + 2];
    }
    red[tid] = lsum;
    __syncthreads();
    for (int s2 = 128; s2 > 0; s2 >>= 1) {
        if (tid < s2) red[tid] += red[tid + s2];
        __syncthreads();
    }
    float inv = 1.0f / red[0];
    for (int b = tid; b < B_SZ; b += 256) {
        size_t base = ((size_t)t * B_SZ + b) * OUTC + 120;
        out[base]     *= inv;
        out[base + 1] *= inv;
        out[base + 2] *= inv;
    }
}

extern "C" void kernel_launch(void* const* d_in, const int* in_sizes, int n_in,
                              void* d_out, int out_size, void* d_ws, size_t ws_size,
                              hipStream_t stream) {
    const float* s         = (const float*)d_in[0];
    const float* eps       = (const float*)d_in[1];
    const float* enc_Wih_f = (const float*)d_in[2];
    const float* enc_Whh_f = (const float*)d_in[3];
    const float* enc_b_f   = (const float*)d_in[4];
    const float* enc_Wih_b = (const float*)d_in[5];
    // d_in[6] enc_Whh_b unused: backward dir contributes only one step from h=0
    const float* enc_b_b   = (const float*)d_in[7];
    const float* W_mu      = (const float*)d_in[8];
    const float* b_mu      = (const float*)d_in[9];
    const float* W_sig     = (const float*)d_in[10];
    const float* b_sig     = (const float*)d_in[11];
    const float* W_h0      = (const float*)d_in[12];
    const float* b_h0      = (const float*)d_in[13];
    const float* dec_Wih   = (const float*)d_in[14];
    const float* dec_Whh   = (const float*)d_in[15];
    const float* dec_b     = (const float*)d_in[16];
    const float* W_out     = (const float*)d_in[17];
    const float* b_out     = (const float*)d_in[18];

    char* ws = (char*)d_ws;
    bf16_t* wih_s_pad   = (bf16_t*)(ws + 0);         // 131072B
    bf16_t* enc_wih_pad = (bf16_t*)(ws + 131072);    // 65536B
    bf16_t* enc_whh_bf  = (bf16_t*)(ws + 196608);    // 524288B
    bf16_t* dec_whh_bf  = (bf16_t*)(ws + 720896);    // 2097152B
    bf16_t* wout_pad    = (bf16_t*)(ws + 2818048);   // 131072B
    bf16_t* h_glob_e    = (bf16_t*)(ws + 2949120);   // 2x1024x256 bf16 = 1MB
    bf16_t* hb          = (bf16_t*)(ws + 3997696);   // 1024x256 bf16
    bf16_t* h_glob_d    = (bf16_t*)(ws + 4521984);   // 2x1024x512 bf16 = 2MB
    float*  z           = (float*) (ws + 6619136);   // 1024x128 f32
    float*  zproj       = (float*) (ws + 7143424);   // 1024x2048 f32 = 8MB
    int*    flags_e     = (int*)   (ws + 15532032);  // 256 ints
    int*    flags_d     = (int*)   (ws + 15533056);  // 256 ints
    // total ws use: ~14.8 MB

    kconv<<<5760, 256, 0, stream>>>(dec_Wih, enc_Wih_f, enc_Whh_f, dec_Whh, W_out,
                                    wih_s_pad, enc_wih_pad, enc_whh_bf, dec_whh_bf,
                                    wout_pad, flags_e, flags_d);
    kencb<<<1024, 256, 0, stream>>>(s, enc_Wih_b, enc_b_b, hb);
    kenc_p<<<256, 256, 0, stream>>>(s, enc_whh_bf, enc_b_f, enc_wih_pad,
                                    h_glob_e, flags_e);
    {
        const bf16_t* hf = h_glob_e + 1024 * 256;   // parity of t=255 is 1
        kv1<<<64, 256, 0, stream>>>(hf, hb, W_mu, b_mu, W_sig, b_sig, eps, z);
    }
    {
        bf16_t* h0_out = h_glob_d + 1024 * 512;     // h(-1) lives at parity 1
        kv2<<<1024, 256, 0, stream>>>(z, W_h0, b_h0, dec_Wih, dec_b, h0_out, zproj);
    }
    kdec_p<<<256, 256, 0, stream>>>(s, dec_whh_bf, wih_s_pad, zproj, wout_pad,
                                    b_out, h_glob_d, flags_d, (float*)d_out);
    kpost<<<2048, 256, 0, stream>>>((float*)d_out);
    kqk<<<256, 256, 0, stream>>>((float*)d_out);
}